// Round 1
// baseline (9886.410 us; speedup 1.0000x reference)
//
#include <hip/hip_runtime.h>
#include <math.h>

// Problem constants
#define B_  32
#define W_  32
#define M_  1024
#define HD_ 64
#define RD_ 32
#define D_  128           // RL*HD
#define NPAIR (B_*M_)     // 32768
#define NCOL (B_*D_)      // 4096  (columns of XP/XG: c = b*128 + d)

__device__ __forceinline__ float sigmoidf_(float x) {
    return 1.0f / (1.0f + __expf(-x));
}
__device__ __forceinline__ float tanhf_(float x) {
    // tanh(x) = 2*sigmoid(2x) - 1 ; exact at +-inf limits
    return 2.0f / (1.0f + __expf(-2.0f * x)) - 1.0f;
}

// ---------------- setup kernels (once per call) ----------------

// Wn[r][d] = g[r] * V[r][d] / ||V[r,:]||2
__global__ __launch_bounds__(128) void wn_kernel(
    const float* __restrict__ V, const float* __restrict__ g,
    float* __restrict__ Wn)
{
    int r = blockIdx.x;
    int d = threadIdx.x;          // 128 threads = 2 waves
    float v = V[r*D_ + d];
    float s = v * v;
    #pragma unroll
    for (int off = 32; off > 0; off >>= 1) s += __shfl_down(s, off);
    __shared__ float ws[2];
    if ((threadIdx.x & 63) == 0) ws[threadIdx.x >> 6] = s;
    __syncthreads();
    float norm = sqrtf(ws[0] + ws[1]);
    Wn[r*D_ + d] = g[r] * v / norm;
}

// gh1c[m][k] = dot(H_init[1,m,:], Whh1[k,:]) + bhh1[k]   (time-invariant)
__global__ __launch_bounds__(192) void gh1c_kernel(
    const float* __restrict__ H_init, const float* __restrict__ Whh1,
    const float* __restrict__ bhh1, float* __restrict__ gh1c)
{
    int m = blockIdx.x;
    int k = threadIdx.x;          // 0..191
    __shared__ float h01[HD_];
    if (k < HD_) h01[k] = H_init[(M_ + m)*HD_ + k];
    __syncthreads();
    float d = 0.f;
    #pragma unroll
    for (int hd = 0; hd < HD_; ++hd) d = fmaf(h01[hd], Whh1[k*HD_ + hd], d);
    gh1c[m*192 + k] = d + bhh1[k];
}

// H[(b*M+m)*64+hd] = H_init[0,m,hd]  (broadcast over batch)
__global__ __launch_bounds__(256) void init_h_kernel(
    const float* __restrict__ H_init, float* __restrict__ H)
{
    int idx = blockIdx.x * 256 + threadIdx.x;   // < 2097152
    H[idx] = H_init[idx & (M_*HD_ - 1)];        // idx % 65536 == m*64+hd
}

// ---------------- per-step kernels ----------------

// GRU layer 0: reads state H (=hn1 of prev step), writes hn0 into XP[:, c<64].
// One 64-lane wave per (b,m) pair; Whh0 transposed in LDS; h broadcast via __shfl.
__global__ __launch_bounds__(256) void gru0_kernel(
    const float* __restrict__ H, const float* __restrict__ x_input,
    const float* __restrict__ Wih0, const float* __restrict__ Whh0,
    const float* __restrict__ bih0, const float* __restrict__ bhh0,
    float* __restrict__ XP, int t)
{
    __shared__ float WT[HD_][192];   // WT[hd][k] = Whh0[k][hd]  (48 KB, bank = (k)%32 -> 2-way, free)
    __shared__ float wi[192], bi[192], bh[192];
    int tid = threadIdx.x;
    for (int idx = tid; idx < 192*HD_; idx += 256)
        WT[idx & 63][idx >> 6] = Whh0[idx];
    if (tid < 192) { wi[tid] = Wih0[tid]; bi[tid] = bih0[tid]; bh[tid] = bhh0[tid]; }
    __syncthreads();
    int g = tid >> 6, j = tid & 63;
    int p0 = blockIdx.x * 64;                    // 512 blocks * 64 pairs
    for (int iter = 0; iter < 16; ++iter) {
        int p = p0 + iter*4 + g;
        int b = p >> 10, m = p & (M_-1);
        float hj = H[p*HD_ + j];
        float x  = x_input[(b*W_ + t)*M_ + m];
        float dr = 0.f, dz = 0.f, dn = 0.f;
        #pragma unroll
        for (int hd = 0; hd < HD_; ++hd) {
            float hv = __shfl(hj, hd);           // unrolled -> v_readlane (SGPR broadcast)
            dr = fmaf(hv, WT[hd][j],       dr);
            dz = fmaf(hv, WT[hd][j +  64], dz);
            dn = fmaf(hv, WT[hd][j + 128], dn);
        }
        float r = sigmoidf_(x*wi[j]      + bi[j]      + dr + bh[j]);
        float z = sigmoidf_(x*wi[j+64]   + bi[j+64]   + dz + bh[j+64]);
        float n = tanhf_  (x*wi[j+128]  + bi[j+128]  + r * (dn + bh[j+128]));
        float hn0 = (1.f - z)*n + z*hj;
        XP[m*NCOL + b*D_ + j] = hn0;
    }
}

// GRU layer 1: reads hn0 from XP, hidden = H_init[1] (time-invariant, gh precomputed).
// Writes hn1 into XP[:, c>=64] AND the recurrent state H.
__global__ __launch_bounds__(256) void gru1_kernel(
    const float* __restrict__ Wih1, const float* __restrict__ bih1,
    const float* __restrict__ gh1c, const float* __restrict__ H_init,
    float* __restrict__ H, float* __restrict__ XP)
{
    __shared__ float WT[HD_][192];   // WT[hd][k] = Wih1[k][hd]
    __shared__ float bi[192];
    int tid = threadIdx.x;
    for (int idx = tid; idx < 192*HD_; idx += 256)
        WT[idx & 63][idx >> 6] = Wih1[idx];
    if (tid < 192) bi[tid] = bih1[tid];
    __syncthreads();
    int g = tid >> 6, j = tid & 63;
    int p0 = blockIdx.x * 64;
    for (int iter = 0; iter < 16; ++iter) {
        int p = p0 + iter*4 + g;
        int b = p >> 10, m = p & (M_-1);
        float aj = XP[m*NCOL + b*D_ + j];        // hn0
        float dr = 0.f, dz = 0.f, dn = 0.f;
        #pragma unroll
        for (int hd = 0; hd < HD_; ++hd) {
            float av = __shfl(aj, hd);
            dr = fmaf(av, WT[hd][j],       dr);
            dz = fmaf(av, WT[hd][j +  64], dz);
            dn = fmaf(av, WT[hd][j + 128], dn);
        }
        const float* gc = &gh1c[m*192];
        float r = sigmoidf_(dr + bi[j]     + gc[j]);
        float z = sigmoidf_(dz + bi[j+64]  + gc[j+64]);
        float n = tanhf_  (dn + bi[j+128] + r * gc[j+128]);
        float h01 = H_init[(M_ + m)*HD_ + j];
        float hn1 = (1.f - z)*n + z*h01;
        H[p*HD_ + j]              = hn1;         // carry for next step
        XP[m*NCOL + b*D_ + 64 + j] = hn1;
    }
}

// XG[j][c] = relu( sum_i G[i][j] * XP[i][c] )   -- 1024 x 4096 x 1024 f32 GEMM
#define GBM 128
#define GBN 64
#define GBK 16
__global__ __launch_bounds__(256) void graph_gemm_relu(
    const float* __restrict__ G, const float* __restrict__ XP,
    float* __restrict__ XG)
{
    __shared__ float As[GBK][GBM + 4];   // As[k][j] = G[k0+k][jt+j]
    __shared__ float Bs[GBK][GBN + 4];   // Bs[k][c] = XP[k0+k][ct+c]
    int tid = threadIdx.x;
    int jt = blockIdx.y * GBM;
    int ct = blockIdx.x * GBN;
    int tx = tid & 7;        // 8 col groups * 8 cols
    int ty = tid >> 3;       // 32 row groups * 4 rows
    float acc[4][8];
    #pragma unroll
    for (int i = 0; i < 4; ++i)
        #pragma unroll
        for (int c = 0; c < 8; ++c) acc[i][c] = 0.f;

    int alr = tid >> 5;            // 0..7 : A loader row (x2)
    int alc = (tid & 31) * 4;      // 0..124
    int blr = tid >> 4;            // 0..15 : B loader row
    int blc = (tid & 15) * 4;      // 0..60

    for (int k0 = 0; k0 < M_; k0 += GBK) {
        *(float4*)&As[alr    ][alc] = *(const float4*)&G[(k0 + alr    )*M_ + jt + alc];
        *(float4*)&As[alr + 8][alc] = *(const float4*)&G[(k0 + alr + 8)*M_ + jt + alc];
        *(float4*)&Bs[blr][blc]     = *(const float4*)&XP[(k0 + blr)*NCOL + ct + blc];
        __syncthreads();
        #pragma unroll
        for (int kk = 0; kk < GBK; ++kk) {
            float4 a  = *(float4*)&As[kk][ty*4];
            float4 b0 = *(float4*)&Bs[kk][tx*8];
            float4 b1 = *(float4*)&Bs[kk][tx*8 + 4];
            float av[4] = {a.x, a.y, a.z, a.w};
            float bv[8] = {b0.x, b0.y, b0.z, b0.w, b1.x, b1.y, b1.z, b1.w};
            #pragma unroll
            for (int i = 0; i < 4; ++i)
                #pragma unroll
                for (int c = 0; c < 8; ++c)
                    acc[i][c] = fmaf(av[i], bv[c], acc[i][c]);
        }
        __syncthreads();
    }
    #pragma unroll
    for (int i = 0; i < 4; ++i) {
        int row = jt + ty*4 + i;
        float4 o0, o1;
        o0.x = fmaxf(acc[i][0], 0.f); o0.y = fmaxf(acc[i][1], 0.f);
        o0.z = fmaxf(acc[i][2], 0.f); o0.w = fmaxf(acc[i][3], 0.f);
        o1.x = fmaxf(acc[i][4], 0.f); o1.y = fmaxf(acc[i][5], 0.f);
        o1.z = fmaxf(acc[i][6], 0.f); o1.w = fmaxf(acc[i][7], 0.f);
        *(float4*)&XG[row*NCOL + ct + tx*8]     = o0;
        *(float4*)&XG[row*NCOL + ct + tx*8 + 4] = o1;
    }
}

// out[b,t,m] = sum_r sigmoid( dot(XG[m][b*128:], Wn[r]) + b_lin[r] ) * W_fr[m][r] + b_fr[m]
__global__ __launch_bounds__(64) void head_kernel(
    const float* __restrict__ XG, const float* __restrict__ Wn,
    const float* __restrict__ b_lin, const float* __restrict__ W_fr,
    const float* __restrict__ b_fr, float* __restrict__ out, int t)
{
    int p = blockIdx.x;
    int b = p >> 10, m = p & (M_-1);
    int tid = threadIdx.x;         // 64
    int r = tid & 31, q = tid >> 5;
    const float* xg = &XG[m*NCOL + b*D_];
    float partial = 0.f;
    #pragma unroll
    for (int d = 0; d < 64; d += 4) {
        float4 xv = *(const float4*)&xg[q*64 + d];
        float4 wv = *(const float4*)&Wn[r*D_ + q*64 + d];
        partial += xv.x*wv.x + xv.y*wv.y + xv.z*wv.z + xv.w*wv.w;
    }
    partial += __shfl_down(partial, 32);
    float y = sigmoidf_(partial + b_lin[r]);      // valid lanes 0..31
    float v = y * W_fr[m*RD_ + r];
    v += __shfl_down(v, 16);
    v += __shfl_down(v, 8);
    v += __shfl_down(v, 4);
    v += __shfl_down(v, 2);
    v += __shfl_down(v, 1);
    if (tid == 0) out[(b*W_ + t)*M_ + m] = v + b_fr[m];
}

// ---------------- launcher ----------------

extern "C" void kernel_launch(void* const* d_in, const int* in_sizes, int n_in,
                              void* d_out, int out_size, void* d_ws, size_t ws_size,
                              hipStream_t stream) {
    const float* x_input = (const float*)d_in[0];
    const float* G       = (const float*)d_in[1];
    const float* H_init  = (const float*)d_in[2];
    const float* Wih0    = (const float*)d_in[3];
    const float* Whh0    = (const float*)d_in[4];
    const float* bih0    = (const float*)d_in[5];
    const float* bhh0    = (const float*)d_in[6];
    const float* Wih1    = (const float*)d_in[7];
    const float* Whh1    = (const float*)d_in[8];
    const float* bih1    = (const float*)d_in[9];
    const float* bhh1    = (const float*)d_in[10];
    const float* V       = (const float*)d_in[11];
    const float* gvec    = (const float*)d_in[12];
    const float* b_lin   = (const float*)d_in[13];
    const float* W_fr    = (const float*)d_in[14];
    const float* b_fr    = (const float*)d_in[15];
    float* out = (float*)d_out;

    // workspace layout (floats, all 16B-aligned): total ~42.7 MB
    float* ws   = (float*)d_ws;
    float* Wn   = ws;                    //     4096
    float* gh1c = ws + 4096;             //   196608
    float* Hst  = ws + 200704;           //  2097152
    float* XP   = ws + 2297856;          //  4194304  [M][B*D]
    float* XG   = ws + 6492160;          //  4194304  [M][B*D]

    wn_kernel  <<<RD_, 128, 0, stream>>>(V, gvec, Wn);
    gh1c_kernel<<<M_, 192, 0, stream>>>(H_init, Whh1, bhh1, gh1c);
    init_h_kernel<<<(NPAIR*HD_)/256, 256, 0, stream>>>(H_init, Hst);

    for (int t = 0; t < W_; ++t) {
        gru0_kernel<<<512, 256, 0, stream>>>(Hst, x_input, Wih0, Whh0, bih0, bhh0, XP, t);
        gru1_kernel<<<512, 256, 0, stream>>>(Wih1, bih1, gh1c, H_init, Hst, XP);
        graph_gemm_relu<<<dim3(NCOL/GBN, M_/GBM), 256, 0, stream>>>(G, XP, XG);
        head_kernel<<<NPAIR, 64, 0, stream>>>(XG, Wn, b_lin, W_fr, b_fr, out, t);
    }
}

// Round 2
// 1399.923 us; speedup vs baseline: 7.0621x; 7.0621x over previous
//
#include <hip/hip_runtime.h>
#include <math.h>

#define B_  32
#define W_  32
#define M_  1024
#define HD_ 64
#define RD_ 32
#define D_  128

typedef short bf16x8 __attribute__((ext_vector_type(8)));
typedef float f32x4  __attribute__((ext_vector_type(4)));

#define AS1 __attribute__((address_space(1)))
#define AS3 __attribute__((address_space(3)))

__device__ __forceinline__ void gload16(const void* g, void* l) {
    __builtin_amdgcn_global_load_lds((const AS1 void*)g, (AS3 void*)l, 16, 0, 0);
}

__device__ __forceinline__ unsigned short f2b(float f) {
    unsigned int u = __float_as_uint(f);
    u += 0x7fffu + ((u >> 16) & 1u);
    return (unsigned short)(u >> 16);
}
__device__ __forceinline__ float b2f(unsigned short h) {
    return __uint_as_float(((unsigned int)h) << 16);
}
__device__ __forceinline__ float sigf(float x) { return 1.0f / (1.0f + __expf(-x)); }
__device__ __forceinline__ float tanhf_(float x) { return 2.0f / (1.0f + __expf(-2.0f * x)) - 1.0f; }

// ---------------- setup kernels ----------------

// GTb[j][i] = bf16(G[i][j])
__global__ __launch_bounds__(256) void gt_kernel(const float* __restrict__ G,
                                                 unsigned short* __restrict__ GTb) {
    __shared__ float T[64][65];
    int i0 = blockIdx.x * 64, j0 = blockIdx.y * 64;
    int tid = threadIdx.x;
    int r = tid >> 4, c4 = (tid & 15) * 4;
    #pragma unroll
    for (int q = 0; q < 4; ++q) {
        float4 v = *(const float4*)&G[(i0 + r + q * 16) * M_ + j0 + c4];
        T[r + q * 16][c4] = v.x; T[r + q * 16][c4 + 1] = v.y;
        T[r + q * 16][c4 + 2] = v.z; T[r + q * 16][c4 + 3] = v.w;
    }
    __syncthreads();
    #pragma unroll
    for (int q = 0; q < 4; ++q) {
        int jr = r + q * 16;
        ushort4 o;
        o.x = f2b(T[c4][jr]); o.y = f2b(T[c4 + 1][jr]);
        o.z = f2b(T[c4 + 2][jr]); o.w = f2b(T[c4 + 3][jr]);
        *(ushort4*)&GTb[(j0 + jr) * M_ + i0 + c4] = o;
    }
}

// gh1cT[k][m] = dot(H_init[1,m,:], Whh1[k,:]) + bhh1[k]
__global__ __launch_bounds__(192) void gh1ct_kernel(const float* __restrict__ H_init,
                                                    const float* __restrict__ Whh1,
                                                    const float* __restrict__ bhh1,
                                                    float* __restrict__ gh1cT) {
    int m = blockIdx.x, k = threadIdx.x;
    __shared__ float h01[HD_];
    if (k < HD_) h01[k] = H_init[(M_ + m) * HD_ + k];
    __syncthreads();
    float d = 0.f;
    #pragma unroll
    for (int hd = 0; hd < HD_; ++hd) d = fmaf(h01[hd], Whh1[k * HD_ + hd], d);
    gh1cT[k * M_ + m] = d + bhh1[k];
}

// Wnb[r][d] = bf16(g[r]*V[r][d]/||V[r,:]||)
__global__ __launch_bounds__(128) void wn_kernel(const float* __restrict__ V,
                                                 const float* __restrict__ g,
                                                 unsigned short* __restrict__ Wnb) {
    int r = blockIdx.x, d = threadIdx.x;
    float v = V[r * D_ + d];
    float s = v * v;
    #pragma unroll
    for (int off = 32; off > 0; off >>= 1) s += __shfl_down(s, off);
    __shared__ float ws[2];
    if ((threadIdx.x & 63) == 0) ws[threadIdx.x >> 6] = s;
    __syncthreads();
    float norm = sqrtf(ws[0] + ws[1]);
    Wnb[r * D_ + d] = f2b(g[r] * v / norm);
}

// bf16 casts of Whh0 and Wih1 (each 192*64 = 12288 elems)
__global__ __launch_bounds__(256) void castw_kernel(const float* __restrict__ Whh0,
                                                    const float* __restrict__ Wih1,
                                                    unsigned short* __restrict__ Whh0b,
                                                    unsigned short* __restrict__ Wih1b) {
    int i = blockIdx.x * 256 + threadIdx.x;  // < 12288
    Whh0b[i] = f2b(Whh0[i]);
    Wih1b[i] = f2b(Wih1[i]);
}

// Hb[p*64+hd] = bf16(H_init[0, p%1024, hd])
__global__ __launch_bounds__(256) void inith_kernel(const float* __restrict__ H_init,
                                                    unsigned short* __restrict__ Hb) {
    int e8 = blockIdx.x * 256 + threadIdx.x;   // 262144 total
    int base = e8 * 8;
    int src = base & (M_ * HD_ - 1);
    float4 v0 = *(const float4*)&H_init[src];
    float4 v1 = *(const float4*)&H_init[src + 4];
    uint4 u;
    u.x = (unsigned int)f2b(v0.x) | ((unsigned int)f2b(v0.y) << 16);
    u.y = (unsigned int)f2b(v0.z) | ((unsigned int)f2b(v0.w) << 16);
    u.z = (unsigned int)f2b(v1.x) | ((unsigned int)f2b(v1.y) << 16);
    u.w = (unsigned int)f2b(v1.z) | ((unsigned int)f2b(v1.w) << 16);
    *(uint4*)&Hb[base] = u;
}

// ---------------- per-step: fused GRU0+GRU1 ----------------
// Block: 64 pairs (one b, 64 consecutive m), 4 waves x 16 pairs.
// MFMA matvecs; gates in-lane f32; writes Hb (bf16 state) + XPT[c][m] bf16.
__global__ __launch_bounds__(256) void grufused_kernel(
    const float* __restrict__ x_input, const float* __restrict__ Wih0,
    const float* __restrict__ bih0, const float* __restrict__ bhh0,
    const unsigned short* __restrict__ Whh0b, const unsigned short* __restrict__ Wih1b,
    const float* __restrict__ bih1, const float* __restrict__ gh1cT,
    const float* __restrict__ H_init, unsigned short* __restrict__ Hb,
    unsigned short* __restrict__ XPT, int t)
{
    __shared__ unsigned short hn0s[64 * 64];
    __shared__ unsigned short hn1s[64 * 64];
    const int tid = threadIdx.x, w = tid >> 6, l = tid & 63;
    const int li = l & 15, lh = l >> 4;
    const int b = blockIdx.x >> 4, mt = blockIdx.x & 15;
    const int m0 = mt * 64;
    const int p0b = b * M_ + m0;
    const int ms = m0 + w * 16;
    const int ps = p0b + w * 16;

    // per-lane constants (gate g3: 0=r,1=z,2=n)
    float wi_[3][4], bi0_[3][4], bh0_[3][4], bi1_[3][4];
    #pragma unroll
    for (int fi = 0; fi < 4; ++fi) {
        int ko = li + 16 * fi;
        #pragma unroll
        for (int g3 = 0; g3 < 3; ++g3) {
            wi_[g3][fi]  = Wih0[g3 * 64 + ko];
            bi0_[g3][fi] = bih0[g3 * 64 + ko];
            bh0_[g3][fi] = bhh0[g3 * 64 + ko];
            bi1_[g3][fi] = bih1[g3 * 64 + ko];
        }
    }
    float4 xv = *(const float4*)&x_input[(b * W_ + t) * M_ + ms + lh * 4];
    float x4[4] = {xv.x, xv.y, xv.z, xv.w};

    // ---- GRU0 matvec: gh0 = Hb_strip (16x64) @ Whh0^T (64x192) ----
    bf16x8 a0_0 = *(const bf16x8*)&Hb[(ps + li) * HD_ + lh * 8];
    bf16x8 a0_1 = *(const bf16x8*)&Hb[(ps + li) * HD_ + 32 + lh * 8];
    f32x4 acc[12];
    #pragma unroll
    for (int nt = 0; nt < 12; ++nt) acc[nt] = (f32x4){0.f, 0.f, 0.f, 0.f};
    #pragma unroll
    for (int nt = 0; nt < 12; ++nt) {
        bf16x8 b0 = *(const bf16x8*)&Whh0b[(nt * 16 + li) * HD_ + lh * 8];
        bf16x8 b1 = *(const bf16x8*)&Whh0b[(nt * 16 + li) * HD_ + 32 + lh * 8];
        acc[nt] = __builtin_amdgcn_mfma_f32_16x16x32_bf16(a0_0, b0, acc[nt], 0, 0, 0);
        acc[nt] = __builtin_amdgcn_mfma_f32_16x16x32_bf16(a0_1, b1, acc[nt], 0, 0, 0);
    }
    // gates (lane holds p=(ps+lh*4+reg), j=(li+16*fi))
    #pragma unroll
    for (int reg = 0; reg < 4; ++reg) {
        int p = ps + lh * 4 + reg;
        int ml = w * 16 + lh * 4 + reg;
        #pragma unroll
        for (int fi = 0; fi < 4; ++fi) {
            int j = li + 16 * fi;
            float hprev = b2f(Hb[p * HD_ + j]);
            float gr = acc[fi][reg]     + bh0_[0][fi];
            float gz = acc[4 + fi][reg] + bh0_[1][fi];
            float gn = acc[8 + fi][reg] + bh0_[2][fi];
            float x = x4[reg];
            float r = sigf(x * wi_[0][fi] + bi0_[0][fi] + gr);
            float z = sigf(x * wi_[1][fi] + bi0_[1][fi] + gz);
            float n = tanhf_(x * wi_[2][fi] + bi0_[2][fi] + r * gn);
            float h0v = (1.f - z) * n + z * hprev;
            int byte = ml * 128 + ((((j >> 3) ^ (ml & 7))) << 4) + (j & 7) * 2;
            *(unsigned short*)((char*)hn0s + byte) = f2b(h0v);
        }
    }
    __syncthreads();

    // ---- GRU1 matvec: gi1 = hn0_strip @ Wih1^T ----
    bf16x8 a1_0, a1_1;
    {
        int row = w * 16 + li;
        int c0 = (0 * 4 + lh) ^ (row & 7);
        int c1 = (1 * 4 + lh) ^ (row & 7);
        a1_0 = *(const bf16x8*)((char*)hn0s + row * 128 + c0 * 16);
        a1_1 = *(const bf16x8*)((char*)hn0s + row * 128 + c1 * 16);
    }
    #pragma unroll
    for (int nt = 0; nt < 12; ++nt) acc[nt] = (f32x4){0.f, 0.f, 0.f, 0.f};
    #pragma unroll
    for (int nt = 0; nt < 12; ++nt) {
        bf16x8 b0 = *(const bf16x8*)&Wih1b[(nt * 16 + li) * HD_ + lh * 8];
        bf16x8 b1 = *(const bf16x8*)&Wih1b[(nt * 16 + li) * HD_ + 32 + lh * 8];
        acc[nt] = __builtin_amdgcn_mfma_f32_16x16x32_bf16(a1_0, b0, acc[nt], 0, 0, 0);
        acc[nt] = __builtin_amdgcn_mfma_f32_16x16x32_bf16(a1_1, b1, acc[nt], 0, 0, 0);
    }
    #pragma unroll
    for (int fi = 0; fi < 4; ++fi) {
        int ko = li + 16 * fi;
        float4 vr = *(const float4*)&gh1cT[(ko) * M_ + ms + lh * 4];
        float4 vz = *(const float4*)&gh1cT[(64 + ko) * M_ + ms + lh * 4];
        float4 vn = *(const float4*)&gh1cT[(128 + ko) * M_ + ms + lh * 4];
        float vrA[4] = {vr.x, vr.y, vr.z, vr.w};
        float vzA[4] = {vz.x, vz.y, vz.z, vz.w};
        float vnA[4] = {vn.x, vn.y, vn.z, vn.w};
        #pragma unroll
        for (int reg = 0; reg < 4; ++reg) {
            int m = ms + lh * 4 + reg;
            int ml = w * 16 + lh * 4 + reg;
            float h01 = H_init[M_ * HD_ + m * HD_ + ko];
            float r = sigf(acc[fi][reg]     + bi1_[0][fi] + vrA[reg]);
            float z = sigf(acc[4 + fi][reg] + bi1_[1][fi] + vzA[reg]);
            float n = tanhf_(acc[8 + fi][reg] + bi1_[2][fi] + r * vnA[reg]);
            float h1v = (1.f - z) * n + z * h01;
            int byte = ml * 128 + ((((ko >> 3) ^ (ml & 7))) << 4) + (ko & 7) * 2;
            *(unsigned short*)((char*)hn1s + byte) = f2b(h1v);
        }
    }
    __syncthreads();

    // ---- outputs: XPT rows (transposed) + Hb state ----
    {
        int d = tid >> 1, mh = (tid & 1) * 32;
        const char* src = (d < 64) ? (const char*)hn0s : (const char*)hn1s;
        int dd = d & 63;
        unsigned int pk[16];
        #pragma unroll
        for (int mm = 0; mm < 32; mm += 2) {
            int ma = mh + mm, mb = mh + mm + 1;
            unsigned int ua = *(const unsigned short*)(src + ma * 128 + (((dd >> 3) ^ (ma & 7)) << 4) + (dd & 7) * 2);
            unsigned int ub = *(const unsigned short*)(src + mb * 128 + (((dd >> 3) ^ (mb & 7)) << 4) + (dd & 7) * 2);
            pk[mm >> 1] = ua | (ub << 16);
        }
        #pragma unroll
        for (int q = 0; q < 4; ++q) {
            uint4 o = {pk[q * 4], pk[q * 4 + 1], pk[q * 4 + 2], pk[q * 4 + 3]};
            *(uint4*)&XPT[(b * D_ + d) * M_ + m0 + mh + q * 8] = o;
        }
    }
    #pragma unroll
    for (int it = 0; it < 2; ++it) {
        int idx = tid + it * 256;
        int p = idx >> 3, cc = idx & 7;
        uint4 v = *(const uint4*)((char*)hn1s + p * 128 + ((cc ^ (p & 7)) << 4));
        *(uint4*)&Hb[(p0b + p) * HD_ + cc * 8] = v;
    }
}

// ---------------- per-step: graph GEMM (MFMA) + fused head ----------------
// grid (32 b, 16 jt); tile 64j x 128c (c-range = batch b's full D); BK=32.
__global__ __launch_bounds__(256) void gemmhead_kernel(
    const unsigned short* __restrict__ GTb, const unsigned short* __restrict__ XPT,
    const unsigned short* __restrict__ Wnb, const float* __restrict__ b_lin,
    const float* __restrict__ W_fr, const float* __restrict__ b_fr,
    float* __restrict__ out, int t)
{
    __shared__ unsigned short As[64 * 32];     // 4 KB
    __shared__ unsigned short Bs[128 * 32];    // 8 KB
    __shared__ unsigned short XGs[64 * 128];   // 16 KB
    const int tid = threadIdx.x, w = tid >> 6, l = tid & 63;
    const int li = l & 15, lh = l >> 4;
    const int b = blockIdx.x, j0 = blockIdx.y * 64;
    const int wj = w >> 1, wc = w & 1;

    f32x4 acc[2][4];
    #pragma unroll
    for (int mi = 0; mi < 2; ++mi)
        #pragma unroll
        for (int ni = 0; ni < 4; ++ni) acc[mi][ni] = (f32x4){0.f, 0.f, 0.f, 0.f};

    for (int k0 = 0; k0 < M_; k0 += 32) {
        {   // stage A tile (64x32), chunk-XOR-swizzled source, linear LDS dest
            int d = w * 64 + l;
            int row = d >> 2, ch = (d & 3) ^ ((row >> 1) & 3);
            gload16(&GTb[(j0 + row) * M_ + k0 + ch * 8], (char*)As + w * 1024);
        }
        #pragma unroll
        for (int rr = 0; rr < 2; ++rr) {   // stage B tile (128x32)
            int d = rr * 256 + w * 64 + l;
            int row = d >> 2, ch = (d & 3) ^ ((row >> 1) & 3);
            gload16(&XPT[(b * D_ + row) * M_ + k0 + ch * 8], (char*)Bs + rr * 4096 + w * 1024);
        }
        __syncthreads();
        bf16x8 af[2], bfv[4];
        #pragma unroll
        for (int mi = 0; mi < 2; ++mi) {
            int row = wj * 32 + mi * 16 + li;
            int ch = lh ^ ((row >> 1) & 3);
            af[mi] = *(const bf16x8*)((char*)As + row * 64 + ch * 16);
        }
        #pragma unroll
        for (int ni = 0; ni < 4; ++ni) {
            int row = wc * 64 + ni * 16 + li;
            int ch = lh ^ ((row >> 1) & 3);
            bfv[ni] = *(const bf16x8*)((char*)Bs + row * 64 + ch * 16);
        }
        #pragma unroll
        for (int mi = 0; mi < 2; ++mi)
            #pragma unroll
            for (int ni = 0; ni < 4; ++ni)
                acc[mi][ni] = __builtin_amdgcn_mfma_f32_16x16x32_bf16(af[mi], bfv[ni], acc[mi][ni], 0, 0, 0);
        __syncthreads();
    }

    // relu -> bf16 -> XGs (swizzled)
    #pragma unroll
    for (int mi = 0; mi < 2; ++mi)
        #pragma unroll
        for (int ni = 0; ni < 4; ++ni)
            #pragma unroll
            for (int reg = 0; reg < 4; ++reg) {
                int jl = wj * 32 + mi * 16 + lh * 4 + reg;
                int c  = wc * 64 + ni * 16 + li;
                float v = fmaxf(acc[mi][ni][reg], 0.f);
                int byte = jl * 256 + ((((c >> 3) ^ (jl & 7))) << 4) + (c & 7) * 2;
                *(unsigned short*)((char*)XGs + byte) = f2b(v);
            }
    __syncthreads();

    // head: P[j][r] = XGs[j][:] . Wnb[r][:]  (wave w: 16 j-rows)
    f32x4 P[2];
    P[0] = (f32x4){0.f, 0.f, 0.f, 0.f};
    P[1] = (f32x4){0.f, 0.f, 0.f, 0.f};
    #pragma unroll
    for (int ks = 0; ks < 4; ++ks) {
        int row = w * 16 + li;
        int chunk = (ks * 4 + lh) ^ (row & 7);
        bf16x8 xa = *(const bf16x8*)((char*)XGs + row * 256 + chunk * 16);
        #pragma unroll
        for (int rt = 0; rt < 2; ++rt) {
            bf16x8 wb = *(const bf16x8*)&Wnb[(rt * 16 + li) * D_ + ks * 32 + lh * 8];
            P[rt] = __builtin_amdgcn_mfma_f32_16x16x32_bf16(xa, wb, P[rt], 0, 0, 0);
        }
    }
    float bl0 = b_lin[li], bl1 = b_lin[16 + li];
    float s[4];
    #pragma unroll
    for (int reg = 0; reg < 4; ++reg) {
        int j = j0 + w * 16 + lh * 4 + reg;
        float y0 = sigf(P[0][reg] + bl0);
        float y1 = sigf(P[1][reg] + bl1);
        s[reg] = y0 * W_fr[j * RD_ + li] + y1 * W_fr[j * RD_ + 16 + li];
    }
    #pragma unroll
    for (int off = 1; off < 16; off <<= 1) {
        #pragma unroll
        for (int reg = 0; reg < 4; ++reg) s[reg] += __shfl_xor(s[reg], off);
    }
    if (li == 0) {
        int jb = j0 + w * 16 + lh * 4;
        float4 o = {s[0] + b_fr[jb], s[1] + b_fr[jb + 1], s[2] + b_fr[jb + 2], s[3] + b_fr[jb + 3]};
        *(float4*)&out[(b * W_ + t) * M_ + jb] = o;
    }
}

// ---------------- launcher ----------------

extern "C" void kernel_launch(void* const* d_in, const int* in_sizes, int n_in,
                              void* d_out, int out_size, void* d_ws, size_t ws_size,
                              hipStream_t stream) {
    const float* x_input = (const float*)d_in[0];
    const float* G       = (const float*)d_in[1];
    const float* H_init  = (const float*)d_in[2];
    const float* Wih0    = (const float*)d_in[3];
    const float* Whh0    = (const float*)d_in[4];
    const float* bih0    = (const float*)d_in[5];
    const float* bhh0    = (const float*)d_in[6];
    const float* Wih1    = (const float*)d_in[7];
    const float* Whh1    = (const float*)d_in[8];
    const float* bih1    = (const float*)d_in[9];
    const float* bhh1    = (const float*)d_in[10];
    const float* V       = (const float*)d_in[11];
    const float* gvec    = (const float*)d_in[12];
    const float* b_lin   = (const float*)d_in[13];
    const float* W_fr    = (const float*)d_in[14];
    const float* b_fr    = (const float*)d_in[15];
    float* out = (float*)d_out;

    char* ws = (char*)d_ws;
    unsigned short* GTb   = (unsigned short*)(ws);                 // 2 MB
    unsigned short* XPT   = (unsigned short*)(ws + 2097152);       // 8 MB
    unsigned short* Hb    = (unsigned short*)(ws + 10485760);      // 4 MB
    float*          gh1cT = (float*)(ws + 14680064);               // 768 KB
    unsigned short* Wnb   = (unsigned short*)(ws + 15466496);      // 8 KB
    unsigned short* Whh0b = (unsigned short*)(ws + 15474688);      // 24 KB
    unsigned short* Wih1b = (unsigned short*)(ws + 15499264);      // 24 KB

    gt_kernel   <<<dim3(16, 16), 256, 0, stream>>>(G, GTb);
    gh1ct_kernel<<<M_, 192, 0, stream>>>(H_init, Whh1, bhh1, gh1cT);
    wn_kernel   <<<RD_, 128, 0, stream>>>(V, gvec, Wnb);
    castw_kernel<<<48, 256, 0, stream>>>(Whh0, Wih1, Whh0b, Wih1b);
    inith_kernel<<<1024, 256, 0, stream>>>(H_init, Hb);

    for (int t = 0; t < W_; ++t) {
        grufused_kernel<<<512, 256, 0, stream>>>(x_input, Wih0, bih0, bhh0, Whh0b,
                                                 Wih1b, bih1, gh1cT, H_init, Hb, XPT, t);
        gemmhead_kernel<<<dim3(32, 16), 256, 0, stream>>>(GTb, XPT, Wnb, b_lin,
                                                          W_fr, b_fr, out, t);
    }
}

// Round 3
// 727.956 us; speedup vs baseline: 13.5810x; 1.9231x over previous
//
#include <hip/hip_runtime.h>
#include <math.h>

#define B_  32
#define W_  32
#define M_  1024
#define HD_ 64
#define RD_ 32
#define D_  128
#define CH_ 8            // time-steps per chunk

typedef short bf16x8 __attribute__((ext_vector_type(8)));
typedef float f32x4  __attribute__((ext_vector_type(4)));

#define AS1 __attribute__((address_space(1)))
#define AS3 __attribute__((address_space(3)))

__device__ __forceinline__ void gload16(const void* g, void* l) {
    __builtin_amdgcn_global_load_lds((const AS1 void*)g, (AS3 void*)l, 16, 0, 0);
}

__device__ __forceinline__ unsigned short f2b(float f) {
    unsigned int u = __float_as_uint(f);
    u += 0x7fffu + ((u >> 16) & 1u);
    return (unsigned short)(u >> 16);
}
__device__ __forceinline__ float b2f(unsigned short h) {
    return __uint_as_float(((unsigned int)h) << 16);
}
__device__ __forceinline__ float sigf(float x) { return 1.0f / (1.0f + __expf(-x)); }
__device__ __forceinline__ float tanhf_(float x) { return 2.0f / (1.0f + __expf(-2.0f * x)) - 1.0f; }

// ---------------- setup kernels ----------------

__global__ __launch_bounds__(256) void gt_kernel(const float* __restrict__ G,
                                                 unsigned short* __restrict__ GTb) {
    __shared__ float T[64][65];
    int i0 = blockIdx.x * 64, j0 = blockIdx.y * 64;
    int tid = threadIdx.x;
    int r = tid >> 4, c4 = (tid & 15) * 4;
    #pragma unroll
    for (int q = 0; q < 4; ++q) {
        float4 v = *(const float4*)&G[(i0 + r + q * 16) * M_ + j0 + c4];
        T[r + q * 16][c4] = v.x; T[r + q * 16][c4 + 1] = v.y;
        T[r + q * 16][c4 + 2] = v.z; T[r + q * 16][c4 + 3] = v.w;
    }
    __syncthreads();
    #pragma unroll
    for (int q = 0; q < 4; ++q) {
        int jr = r + q * 16;
        ushort4 o;
        o.x = f2b(T[c4][jr]); o.y = f2b(T[c4 + 1][jr]);
        o.z = f2b(T[c4 + 2][jr]); o.w = f2b(T[c4 + 3][jr]);
        *(ushort4*)&GTb[(j0 + jr) * M_ + i0 + c4] = o;
    }
}

__global__ __launch_bounds__(192) void gh1ct_kernel(const float* __restrict__ H_init,
                                                    const float* __restrict__ Whh1,
                                                    const float* __restrict__ bhh1,
                                                    float* __restrict__ gh1cT) {
    int m = blockIdx.x, k = threadIdx.x;
    __shared__ float h01[HD_];
    if (k < HD_) h01[k] = H_init[(M_ + m) * HD_ + k];
    __syncthreads();
    float d = 0.f;
    #pragma unroll
    for (int hd = 0; hd < HD_; ++hd) d = fmaf(h01[hd], Whh1[k * HD_ + hd], d);
    gh1cT[k * M_ + m] = d + bhh1[k];
}

__global__ __launch_bounds__(128) void wn_kernel(const float* __restrict__ V,
                                                 const float* __restrict__ g,
                                                 unsigned short* __restrict__ Wnb) {
    int r = blockIdx.x, d = threadIdx.x;
    float v = V[r * D_ + d];
    float s = v * v;
    #pragma unroll
    for (int off = 32; off > 0; off >>= 1) s += __shfl_down(s, off);
    __shared__ float ws[2];
    if ((threadIdx.x & 63) == 0) ws[threadIdx.x >> 6] = s;
    __syncthreads();
    float norm = sqrtf(ws[0] + ws[1]);
    Wnb[r * D_ + d] = f2b(g[r] * v / norm);
}

__global__ __launch_bounds__(256) void castw_kernel(const float* __restrict__ Whh0,
                                                    const float* __restrict__ Wih1,
                                                    unsigned short* __restrict__ Whh0b,
                                                    unsigned short* __restrict__ Wih1b) {
    int i = blockIdx.x * 256 + threadIdx.x;  // < 12288
    Whh0b[i] = f2b(Whh0[i]);
    Wih1b[i] = f2b(Wih1[i]);
}

__global__ __launch_bounds__(256) void inith_kernel(const float* __restrict__ H_init,
                                                    unsigned short* __restrict__ Hb) {
    int e8 = blockIdx.x * 256 + threadIdx.x;   // 262144 total
    int base = e8 * 8;
    int src = base & (M_ * HD_ - 1);
    float4 v0 = *(const float4*)&H_init[src];
    float4 v1 = *(const float4*)&H_init[src + 4];
    uint4 u;
    u.x = (unsigned int)f2b(v0.x) | ((unsigned int)f2b(v0.y) << 16);
    u.y = (unsigned int)f2b(v0.z) | ((unsigned int)f2b(v0.w) << 16);
    u.z = (unsigned int)f2b(v1.x) | ((unsigned int)f2b(v1.y) << 16);
    u.w = (unsigned int)f2b(v1.z) | ((unsigned int)f2b(v1.w) << 16);
    *(uint4*)&Hb[base] = u;
}

// ---------------- per-chunk: fused GRU0+GRU1, 8 time-steps ----------------
// 512 blocks x 256 thr (4 waves, 64 pairs: one b, 64 consecutive m).
// Weights in LDS (swizzled via pre-swizzled-source gload16); state in LDS
// across steps; writes XPT for each step; Hb only at chunk end.
__global__ __launch_bounds__(256) void gru_chunk_kernel(
    const float* __restrict__ x_input, const float* __restrict__ Wih0,
    const float* __restrict__ bih0, const float* __restrict__ bhh0,
    const unsigned short* __restrict__ Whh0b, const unsigned short* __restrict__ Wih1b,
    const float* __restrict__ bih1, const float* __restrict__ gh1cT,
    const float* __restrict__ H_init, unsigned short* __restrict__ Hb,
    unsigned short* __restrict__ XPT_c, int t0)
{
    __shared__ unsigned short Whh0s[192 * 64];   // 24 KB, swizzled rows of 8x16B
    __shared__ unsigned short Wih1s[192 * 64];   // 24 KB
    __shared__ unsigned short hn0s[64 * 64];     // 8 KB, swizzled
    __shared__ unsigned short hn1s[64 * 64];     // 8 KB, swizzled (current state)
    const int tid = threadIdx.x, w = tid >> 6, l = tid & 63;
    const int li = l & 15, lh = l >> 4;
    const int b = blockIdx.x >> 4, mt = blockIdx.x & 15;
    const int m0 = mt * 64;
    const int p0b = b * M_ + m0;
    const int ms = m0 + w * 16;

    // weights -> LDS, pre-swizzled source so linear dest = swizzled layout
    for (int i = tid; i < 1536; i += 256) {
        int row = i >> 3, pos = i & 7, sc = pos ^ (row & 7);
        gload16(&Whh0b[row * 64 + sc * 8], (char*)Whh0s + (i & ~63) * 16);
        gload16(&Wih1b[row * 64 + sc * 8], (char*)Wih1s + (i & ~63) * 16);
    }
    // state -> hn1s (swizzled)
    for (int idx = tid; idx < 512; idx += 256) {
        int p = idx >> 3, cc = idx & 7;
        uint4 v = *(const uint4*)&Hb[(p0b + p) * HD_ + cc * 8];
        *(uint4*)((char*)hn1s + p * 128 + ((cc ^ (p & 7)) << 4)) = v;
    }

    // per-lane gate constants (gate: 0=r,1=z,2=n), k-offset ko = li+16*fi
    float wi_[3][4], bi0_[3][4], bh0_[3][4], bi1_[3][4];
    #pragma unroll
    for (int fi = 0; fi < 4; ++fi) {
        int ko = li + 16 * fi;
        #pragma unroll
        for (int g3 = 0; g3 < 3; ++g3) {
            wi_[g3][fi]  = Wih0[g3 * 64 + ko];
            bi0_[g3][fi] = bih0[g3 * 64 + ko];
            bh0_[g3][fi] = bhh0[g3 * 64 + ko];
            bi1_[g3][fi] = bih1[g3 * 64 + ko];
        }
    }

    for (int ts = 0; ts < CH_; ++ts) {
        int t = t0 + ts;
        __syncthreads();   // state/weights ready; prev XPT reads done

        float4 xv = *(const float4*)&x_input[(b * W_ + t) * M_ + ms + lh * 4];
        float x4[4] = {xv.x, xv.y, xv.z, xv.w};

        // ---- GRU0 matvec: gh0 = h_state(16x64) @ Whh0^T ----
        bf16x8 a0_0, a0_1;
        {
            int row = w * 16 + li;
            a0_0 = *(const bf16x8*)((char*)hn1s + row * 128 + ((lh ^ (row & 7)) << 4));
            a0_1 = *(const bf16x8*)((char*)hn1s + row * 128 + (((4 + lh) ^ (row & 7)) << 4));
        }
        f32x4 acc[12];
        #pragma unroll
        for (int nt = 0; nt < 12; ++nt) acc[nt] = (f32x4){0.f, 0.f, 0.f, 0.f};
        #pragma unroll
        for (int nt = 0; nt < 12; ++nt) {
            int row = nt * 16 + li;
            bf16x8 b0 = *(const bf16x8*)((char*)Whh0s + row * 128 + ((lh ^ (row & 7)) << 4));
            bf16x8 b1 = *(const bf16x8*)((char*)Whh0s + row * 128 + (((4 + lh) ^ (row & 7)) << 4));
            acc[nt] = __builtin_amdgcn_mfma_f32_16x16x32_bf16(a0_0, b0, acc[nt], 0, 0, 0);
            acc[nt] = __builtin_amdgcn_mfma_f32_16x16x32_bf16(a0_1, b1, acc[nt], 0, 0, 0);
        }
        // gates gru0 (lane holds local row ml = w*16+lh*4+reg, col j = li+16*fi)
        #pragma unroll
        for (int reg = 0; reg < 4; ++reg) {
            int ml = w * 16 + lh * 4 + reg;
            #pragma unroll
            for (int fi = 0; fi < 4; ++fi) {
                int j = li + 16 * fi;
                float hprev = b2f(*(const unsigned short*)((char*)hn1s + ml * 128 +
                                  ((((j >> 3) ^ (ml & 7))) << 4) + (j & 7) * 2));
                float gr = acc[fi][reg]     + bh0_[0][fi];
                float gz = acc[4 + fi][reg] + bh0_[1][fi];
                float gn = acc[8 + fi][reg] + bh0_[2][fi];
                float x = x4[reg];
                float r = sigf(x * wi_[0][fi] + bi0_[0][fi] + gr);
                float z = sigf(x * wi_[1][fi] + bi0_[1][fi] + gz);
                float n = tanhf_(x * wi_[2][fi] + bi0_[2][fi] + r * gn);
                float h0v = (1.f - z) * n + z * hprev;
                *(unsigned short*)((char*)hn0s + ml * 128 +
                    ((((j >> 3) ^ (ml & 7))) << 4) + (j & 7) * 2) = f2b(h0v);
            }
        }
        __syncthreads();   // hn0s ready; old hn1s fully consumed

        // ---- GRU1 matvec: gi1 = hn0(16x64) @ Wih1^T ----
        bf16x8 a1_0, a1_1;
        {
            int row = w * 16 + li;
            a1_0 = *(const bf16x8*)((char*)hn0s + row * 128 + ((lh ^ (row & 7)) << 4));
            a1_1 = *(const bf16x8*)((char*)hn0s + row * 128 + (((4 + lh) ^ (row & 7)) << 4));
        }
        #pragma unroll
        for (int nt = 0; nt < 12; ++nt) acc[nt] = (f32x4){0.f, 0.f, 0.f, 0.f};
        #pragma unroll
        for (int nt = 0; nt < 12; ++nt) {
            int row = nt * 16 + li;
            bf16x8 b0 = *(const bf16x8*)((char*)Wih1s + row * 128 + ((lh ^ (row & 7)) << 4));
            bf16x8 b1 = *(const bf16x8*)((char*)Wih1s + row * 128 + (((4 + lh) ^ (row & 7)) << 4));
            acc[nt] = __builtin_amdgcn_mfma_f32_16x16x32_bf16(a1_0, b0, acc[nt], 0, 0, 0);
            acc[nt] = __builtin_amdgcn_mfma_f32_16x16x32_bf16(a1_1, b1, acc[nt], 0, 0, 0);
        }
        #pragma unroll
        for (int fi = 0; fi < 4; ++fi) {
            int ko = li + 16 * fi;
            float4 vr = *(const float4*)&gh1cT[(ko) * M_ + ms + lh * 4];
            float4 vz = *(const float4*)&gh1cT[(64 + ko) * M_ + ms + lh * 4];
            float4 vn = *(const float4*)&gh1cT[(128 + ko) * M_ + ms + lh * 4];
            float vrA[4] = {vr.x, vr.y, vr.z, vr.w};
            float vzA[4] = {vz.x, vz.y, vz.z, vz.w};
            float vnA[4] = {vn.x, vn.y, vn.z, vn.w};
            #pragma unroll
            for (int reg = 0; reg < 4; ++reg) {
                int m = ms + lh * 4 + reg;
                int ml = w * 16 + lh * 4 + reg;
                float h01 = H_init[M_ * HD_ + m * HD_ + ko];
                float r = sigf(acc[fi][reg]     + bi1_[0][fi] + vrA[reg]);
                float z = sigf(acc[4 + fi][reg] + bi1_[1][fi] + vzA[reg]);
                float n = tanhf_(acc[8 + fi][reg] + bi1_[2][fi] + r * vnA[reg]);
                float h1v = (1.f - z) * n + z * h01;
                *(unsigned short*)((char*)hn1s + ml * 128 +
                    ((((ko >> 3) ^ (ml & 7))) << 4) + (ko & 7) * 2) = f2b(h1v);
            }
        }
        __syncthreads();   // hn1s (new state) ready

        // ---- XPT write (transposed bf16 rows [c][m]) ----
        {
            unsigned short* XPT = XPT_c + (size_t)ts * (D_ * B_ * M_);
            int d = tid >> 1, mh = (tid & 1) * 32;
            const char* src = (d < 64) ? (const char*)hn0s : (const char*)hn1s;
            int dd = d & 63;
            unsigned int pk[16];
            #pragma unroll
            for (int mm = 0; mm < 32; mm += 2) {
                int ma = mh + mm, mb = mh + mm + 1;
                unsigned int ua = *(const unsigned short*)(src + ma * 128 + (((dd >> 3) ^ (ma & 7)) << 4) + (dd & 7) * 2);
                unsigned int ub = *(const unsigned short*)(src + mb * 128 + (((dd >> 3) ^ (mb & 7)) << 4) + (dd & 7) * 2);
                pk[mm >> 1] = ua | (ub << 16);
            }
            #pragma unroll
            for (int q = 0; q < 4; ++q) {
                uint4 o = {pk[q * 4], pk[q * 4 + 1], pk[q * 4 + 2], pk[q * 4 + 3]};
                *(uint4*)&XPT[(b * D_ + d) * M_ + m0 + mh + q * 8] = o;
            }
        }
    }

    // state writeback for next chunk
    #pragma unroll
    for (int it = 0; it < 2; ++it) {
        int idx = tid + it * 256;
        int p = idx >> 3, cc = idx & 7;
        uint4 v = *(const uint4*)((char*)hn1s + p * 128 + ((cc ^ (p & 7)) << 4));
        *(uint4*)&Hb[(p0b + p) * HD_ + cc * 8] = v;
    }
}

// ---------------- per-chunk: graph GEMM (MFMA, 128x128 tile) + fused head ----
// grid (b*8+ts : 256, j-tile : 8); each block: C[j0..j0+127][b's 128 cols] @ step ts.
__global__ __launch_bounds__(256) void gemmhead_kernel(
    const unsigned short* __restrict__ GTb, const unsigned short* __restrict__ XPT_c,
    const unsigned short* __restrict__ Wnb, const float* __restrict__ b_lin,
    const float* __restrict__ W_fr, const float* __restrict__ b_fr,
    float* __restrict__ out, int t0)
{
    __shared__ unsigned short As[128 * 32];    // 8 KB
    __shared__ unsigned short Bs[128 * 32];    // 8 KB
    __shared__ unsigned short XGs[128 * 128];  // 32 KB
    const int tid = threadIdx.x, w = tid >> 6, l = tid & 63;
    const int li = l & 15, lh = l >> 4;
    const int b = blockIdx.x >> 3, ts = blockIdx.x & 7;
    const int j0 = blockIdx.y * 128;
    const unsigned short* XPTb = XPT_c + (size_t)ts * (D_ * B_ * M_) + (size_t)b * D_ * M_;

    f32x4 acc[2][8];
    #pragma unroll
    for (int mi = 0; mi < 2; ++mi)
        #pragma unroll
        for (int ni = 0; ni < 8; ++ni) acc[mi][ni] = (f32x4){0.f, 0.f, 0.f, 0.f};

    for (int k0 = 0; k0 < M_; k0 += 32) {
        #pragma unroll
        for (int rr = 0; rr < 2; ++rr) {   // stage A(128x32) + B(128x32)
            int d = rr * 256 + tid;
            int row = d >> 2, ch = (d & 3) ^ ((row >> 1) & 3);
            gload16(&GTb[(j0 + row) * M_ + k0 + ch * 8], (char*)As + (d & ~63) * 16);
            gload16(&XPTb[row * M_ + k0 + ch * 8],       (char*)Bs + (d & ~63) * 16);
        }
        __syncthreads();
        bf16x8 af[2], bfv[8];
        #pragma unroll
        for (int mi = 0; mi < 2; ++mi) {
            int row = w * 32 + mi * 16 + li;
            int ch = lh ^ ((row >> 1) & 3);
            af[mi] = *(const bf16x8*)((char*)As + row * 64 + ch * 16);
        }
        #pragma unroll
        for (int ni = 0; ni < 8; ++ni) {
            int row = ni * 16 + li;
            int ch = lh ^ ((row >> 1) & 3);
            bfv[ni] = *(const bf16x8*)((char*)Bs + row * 64 + ch * 16);
        }
        #pragma unroll
        for (int mi = 0; mi < 2; ++mi)
            #pragma unroll
            for (int ni = 0; ni < 8; ++ni)
                acc[mi][ni] = __builtin_amdgcn_mfma_f32_16x16x32_bf16(af[mi], bfv[ni], acc[mi][ni], 0, 0, 0);
        __syncthreads();
    }

    // relu -> bf16 -> XGs (swizzled: 16 chunks/row, XOR low3 with row&7)
    #pragma unroll
    for (int mi = 0; mi < 2; ++mi)
        #pragma unroll
        for (int ni = 0; ni < 8; ++ni)
            #pragma unroll
            for (int reg = 0; reg < 4; ++reg) {
                int jl = w * 32 + mi * 16 + lh * 4 + reg;
                int c  = ni * 16 + li;
                float v = fmaxf(acc[mi][ni][reg], 0.f);
                int byte = jl * 256 + ((((c >> 3) ^ (jl & 7))) << 4) + (c & 7) * 2;
                *(unsigned short*)((char*)XGs + byte) = f2b(v);
            }
    __syncthreads();

    // head: P[j][r] = XGs[j][:] . Wnb[r][:]; wave w handles 32 j-rows (2 groups of 16)
    float bl0 = b_lin[li], bl1 = b_lin[16 + li];
    int t = t0 + ts;
    #pragma unroll
    for (int rg = 0; rg < 2; ++rg) {
        f32x4 P0 = (f32x4){0.f, 0.f, 0.f, 0.f};
        f32x4 P1 = (f32x4){0.f, 0.f, 0.f, 0.f};
        int row = w * 32 + rg * 16 + li;
        #pragma unroll
        for (int ks = 0; ks < 4; ++ks) {
            int pos = (ks * 4 + lh) ^ (row & 7);
            bf16x8 xa = *(const bf16x8*)((char*)XGs + row * 256 + pos * 16);
            bf16x8 wb0 = *(const bf16x8*)&Wnb[(li) * D_ + ks * 32 + lh * 8];
            bf16x8 wb1 = *(const bf16x8*)&Wnb[(16 + li) * D_ + ks * 32 + lh * 8];
            P0 = __builtin_amdgcn_mfma_f32_16x16x32_bf16(xa, wb0, P0, 0, 0, 0);
            P1 = __builtin_amdgcn_mfma_f32_16x16x32_bf16(xa, wb1, P1, 0, 0, 0);
        }
        float s[4];
        #pragma unroll
        for (int reg = 0; reg < 4; ++reg) {
            int j = j0 + w * 32 + rg * 16 + lh * 4 + reg;
            float y0 = sigf(P0[reg] + bl0);
            float y1 = sigf(P1[reg] + bl1);
            s[reg] = y0 * W_fr[j * RD_ + li] + y1 * W_fr[j * RD_ + 16 + li];
        }
        #pragma unroll
        for (int off = 1; off < 16; off <<= 1) {
            #pragma unroll
            for (int reg = 0; reg < 4; ++reg) s[reg] += __shfl_xor(s[reg], off);
        }
        if (li == 0) {
            int jb = j0 + w * 32 + rg * 16 + lh * 4;
            float4 o = {s[0] + b_fr[jb], s[1] + b_fr[jb + 1],
                        s[2] + b_fr[jb + 2], s[3] + b_fr[jb + 3]};
            *(float4*)&out[(b * W_ + t) * M_ + jb] = o;
        }
    }
}

// ---------------- launcher ----------------

extern "C" void kernel_launch(void* const* d_in, const int* in_sizes, int n_in,
                              void* d_out, int out_size, void* d_ws, size_t ws_size,
                              hipStream_t stream) {
    const float* x_input = (const float*)d_in[0];
    const float* G       = (const float*)d_in[1];
    const float* H_init  = (const float*)d_in[2];
    const float* Wih0    = (const float*)d_in[3];
    const float* Whh0    = (const float*)d_in[4];
    const float* bih0    = (const float*)d_in[5];
    const float* bhh0    = (const float*)d_in[6];
    const float* Wih1    = (const float*)d_in[7];
    const float* Whh1    = (const float*)d_in[8];
    const float* bih1    = (const float*)d_in[9];
    const float* bhh1    = (const float*)d_in[10];
    const float* V       = (const float*)d_in[11];
    const float* gvec    = (const float*)d_in[12];
    const float* b_lin   = (const float*)d_in[13];
    const float* W_fr    = (const float*)d_in[14];
    const float* b_fr    = (const float*)d_in[15];
    float* out = (float*)d_out;

    // ws layout (bytes); total ~71 MiB (d_ws observed to be 256 MiB via poison fill)
    char* ws = (char*)d_ws;
    unsigned short* GTb   = (unsigned short*)(ws);                  //  2 MiB
    unsigned short* XPT_c = (unsigned short*)(ws + (2u << 20));     // 64 MiB (8 steps x 8 MiB)
    unsigned short* Hb    = (unsigned short*)(ws + (66u << 20));    //  4 MiB
    float*          gh1cT = (float*)(ws + (70u << 20));             // 768 KiB
    unsigned short* Wnb   = (unsigned short*)(ws + (71u << 20));    //  8 KiB
    unsigned short* Whh0b = (unsigned short*)(ws + (71u << 20) + 8192);
    unsigned short* Wih1b = (unsigned short*)(ws + (71u << 20) + 8192 + 24576);

    gt_kernel   <<<dim3(16, 16), 256, 0, stream>>>(G, GTb);
    gh1ct_kernel<<<M_, 192, 0, stream>>>(H_init, Whh1, bhh1, gh1cT);
    wn_kernel   <<<RD_, 128, 0, stream>>>(V, gvec, Wnb);
    castw_kernel<<<48, 256, 0, stream>>>(Whh0, Wih1, Whh0b, Wih1b);
    inith_kernel<<<1024, 256, 0, stream>>>(H_init, Hb);

    for (int c = 0; c < W_ / CH_; ++c) {
        gru_chunk_kernel<<<512, 256, 0, stream>>>(x_input, Wih0, bih0, bhh0, Whh0b,
                                                  Wih1b, bih1, gh1cT, H_init, Hb,
                                                  XPT_c, c * CH_);
        gemmhead_kernel<<<dim3(256, 8), 256, 0, stream>>>(GTb, XPT_c, Wnb, b_lin,
                                                          W_fr, b_fr, out, c * CH_);
    }
}

// Round 4
// 627.602 us; speedup vs baseline: 15.7527x; 1.1599x over previous
//
#include <hip/hip_runtime.h>
#include <math.h>

#define B_  32
#define W_  32
#define M_  1024
#define HD_ 64
#define RD_ 32
#define D_  128
#define CH_ 16           // time-steps per chunk (2 chunks)
#define NKT 32           // K-tiles (K=1024, BK=32) in gemm

typedef short bf16x8 __attribute__((ext_vector_type(8)));
typedef float f32x4  __attribute__((ext_vector_type(4)));

#define AS1 __attribute__((address_space(1)))
#define AS3 __attribute__((address_space(3)))

__device__ __forceinline__ void gload16(const void* g, void* l) {
    __builtin_amdgcn_global_load_lds((const AS1 void*)g, (AS3 void*)l, 16, 0, 0);
}

__device__ __forceinline__ unsigned short f2b(float f) {
    unsigned int u = __float_as_uint(f);
    u += 0x7fffu + ((u >> 16) & 1u);
    return (unsigned short)(u >> 16);
}
__device__ __forceinline__ float b2f(unsigned short h) {
    return __uint_as_float(((unsigned int)h) << 16);
}
__device__ __forceinline__ float sigf(float x) { return 1.0f / (1.0f + __expf(-x)); }
__device__ __forceinline__ float tanhf_(float x) { return 2.0f / (1.0f + __expf(-2.0f * x)) - 1.0f; }

// ---------------- setup kernels ----------------

__global__ __launch_bounds__(256) void gt_kernel(const float* __restrict__ G,
                                                 unsigned short* __restrict__ GTb) {
    __shared__ float T[64][65];
    int i0 = blockIdx.x * 64, j0 = blockIdx.y * 64;
    int tid = threadIdx.x;
    int r = tid >> 4, c4 = (tid & 15) * 4;
    #pragma unroll
    for (int q = 0; q < 4; ++q) {
        float4 v = *(const float4*)&G[(i0 + r + q * 16) * M_ + j0 + c4];
        T[r + q * 16][c4] = v.x; T[r + q * 16][c4 + 1] = v.y;
        T[r + q * 16][c4 + 2] = v.z; T[r + q * 16][c4 + 3] = v.w;
    }
    __syncthreads();
    #pragma unroll
    for (int q = 0; q < 4; ++q) {
        int jr = r + q * 16;
        ushort4 o;
        o.x = f2b(T[c4][jr]); o.y = f2b(T[c4 + 1][jr]);
        o.z = f2b(T[c4 + 2][jr]); o.w = f2b(T[c4 + 3][jr]);
        *(ushort4*)&GTb[(j0 + jr) * M_ + i0 + c4] = o;
    }
}

__global__ __launch_bounds__(192) void gh1ct_kernel(const float* __restrict__ H_init,
                                                    const float* __restrict__ Whh1,
                                                    const float* __restrict__ bhh1,
                                                    float* __restrict__ gh1cT) {
    int m = blockIdx.x, k = threadIdx.x;
    __shared__ float h01[HD_];
    if (k < HD_) h01[k] = H_init[(M_ + m) * HD_ + k];
    __syncthreads();
    float d = 0.f;
    #pragma unroll
    for (int hd = 0; hd < HD_; ++hd) d = fmaf(h01[hd], Whh1[k * HD_ + hd], d);
    gh1cT[k * M_ + m] = d + bhh1[k];
}

__global__ __launch_bounds__(128) void wn_kernel(const float* __restrict__ V,
                                                 const float* __restrict__ g,
                                                 unsigned short* __restrict__ Wnb) {
    int r = blockIdx.x, d = threadIdx.x;
    float v = V[r * D_ + d];
    float s = v * v;
    #pragma unroll
    for (int off = 32; off > 0; off >>= 1) s += __shfl_down(s, off);
    __shared__ float ws[2];
    if ((threadIdx.x & 63) == 0) ws[threadIdx.x >> 6] = s;
    __syncthreads();
    float norm = sqrtf(ws[0] + ws[1]);
    Wnb[r * D_ + d] = f2b(g[r] * v / norm);
}

__global__ __launch_bounds__(256) void castw_kernel(const float* __restrict__ Whh0,
                                                    const float* __restrict__ Wih1,
                                                    unsigned short* __restrict__ Whh0b,
                                                    unsigned short* __restrict__ Wih1b) {
    int i = blockIdx.x * 256 + threadIdx.x;  // < 12288
    Whh0b[i] = f2b(Whh0[i]);
    Wih1b[i] = f2b(Wih1[i]);
}

__global__ __launch_bounds__(256) void inith_kernel(const float* __restrict__ H_init,
                                                    unsigned short* __restrict__ Hb) {
    int e8 = blockIdx.x * 256 + threadIdx.x;   // 262144 total
    int base = e8 * 8;
    int src = base & (M_ * HD_ - 1);
    float4 v0 = *(const float4*)&H_init[src];
    float4 v1 = *(const float4*)&H_init[src + 4];
    uint4 u;
    u.x = (unsigned int)f2b(v0.x) | ((unsigned int)f2b(v0.y) << 16);
    u.y = (unsigned int)f2b(v0.z) | ((unsigned int)f2b(v0.w) << 16);
    u.z = (unsigned int)f2b(v1.x) | ((unsigned int)f2b(v1.y) << 16);
    u.w = (unsigned int)f2b(v1.z) | ((unsigned int)f2b(v1.w) << 16);
    *(uint4*)&Hb[base] = u;
}

// ---------------- per-chunk: fused GRU0+GRU1, 16 time-steps ----------------
__global__ __launch_bounds__(256) void gru_chunk_kernel(
    const float* __restrict__ x_input, const float* __restrict__ Wih0,
    const float* __restrict__ bih0, const float* __restrict__ bhh0,
    const unsigned short* __restrict__ Whh0b, const unsigned short* __restrict__ Wih1b,
    const float* __restrict__ bih1, const float* __restrict__ gh1cT,
    const float* __restrict__ H_init, unsigned short* __restrict__ Hb,
    unsigned short* __restrict__ XPT_c, int t0)
{
    __shared__ unsigned short Whh0s[192 * 64];   // 24 KB, swizzled rows of 8x16B
    __shared__ unsigned short Wih1s[192 * 64];   // 24 KB
    __shared__ unsigned short hn0s[64 * 64];     // 8 KB, swizzled
    __shared__ unsigned short hn1s[64 * 64];     // 8 KB, swizzled (current state)
    const int tid = threadIdx.x, w = tid >> 6, l = tid & 63;
    const int li = l & 15, lh = l >> 4;
    const int b = blockIdx.x >> 4, mt = blockIdx.x & 15;
    const int m0 = mt * 64;
    const int p0b = b * M_ + m0;
    const int ms = m0 + w * 16;

    // weights -> LDS, pre-swizzled source so linear dest = swizzled layout
    for (int i = tid; i < 1536; i += 256) {
        int row = i >> 3, pos = i & 7, sc = pos ^ (row & 7);
        gload16(&Whh0b[row * 64 + sc * 8], (char*)Whh0s + (i & ~63) * 16);
        gload16(&Wih1b[row * 64 + sc * 8], (char*)Wih1s + (i & ~63) * 16);
    }
    // state -> hn1s (swizzled)
    for (int idx = tid; idx < 512; idx += 256) {
        int p = idx >> 3, cc = idx & 7;
        uint4 v = *(const uint4*)&Hb[(p0b + p) * HD_ + cc * 8];
        *(uint4*)((char*)hn1s + p * 128 + ((cc ^ (p & 7)) << 4)) = v;
    }

    // per-lane gate constants (gate: 0=r,1=z,2=n), k-offset ko = li+16*fi
    float wi_[3][4], bi0_[3][4], bh0_[3][4], bi1_[3][4];
    // loop-invariant hoists: gh1cT terms + H_init[1] (64+16 regs)
    float vrA[4][4], vzA[4][4], vnA[4][4], h01A[4][4];
    #pragma unroll
    for (int fi = 0; fi < 4; ++fi) {
        int ko = li + 16 * fi;
        #pragma unroll
        for (int g3 = 0; g3 < 3; ++g3) {
            wi_[g3][fi]  = Wih0[g3 * 64 + ko];
            bi0_[g3][fi] = bih0[g3 * 64 + ko];
            bh0_[g3][fi] = bhh0[g3 * 64 + ko];
            bi1_[g3][fi] = bih1[g3 * 64 + ko];
        }
        float4 vr = *(const float4*)&gh1cT[(ko) * M_ + ms + lh * 4];
        float4 vz = *(const float4*)&gh1cT[(64 + ko) * M_ + ms + lh * 4];
        float4 vn = *(const float4*)&gh1cT[(128 + ko) * M_ + ms + lh * 4];
        vrA[fi][0] = vr.x; vrA[fi][1] = vr.y; vrA[fi][2] = vr.z; vrA[fi][3] = vr.w;
        vzA[fi][0] = vz.x; vzA[fi][1] = vz.y; vzA[fi][2] = vz.z; vzA[fi][3] = vz.w;
        vnA[fi][0] = vn.x; vnA[fi][1] = vn.y; vnA[fi][2] = vn.z; vnA[fi][3] = vn.w;
        #pragma unroll
        for (int reg = 0; reg < 4; ++reg)
            h01A[fi][reg] = H_init[M_ * HD_ + (ms + lh * 4 + reg) * HD_ + ko];
    }

    for (int ts = 0; ts < CH_; ++ts) {
        int t = t0 + ts;
        __syncthreads();   // state/weights ready; prev XPT reads done

        float4 xv = *(const float4*)&x_input[(b * W_ + t) * M_ + ms + lh * 4];
        float x4[4] = {xv.x, xv.y, xv.z, xv.w};

        // ---- GRU0 matvec: gh0 = h_state(16x64) @ Whh0^T ----
        bf16x8 a0_0, a0_1;
        {
            int row = w * 16 + li;
            a0_0 = *(const bf16x8*)((char*)hn1s + row * 128 + ((lh ^ (row & 7)) << 4));
            a0_1 = *(const bf16x8*)((char*)hn1s + row * 128 + (((4 + lh) ^ (row & 7)) << 4));
        }
        f32x4 acc[12];
        #pragma unroll
        for (int nt = 0; nt < 12; ++nt) acc[nt] = (f32x4){0.f, 0.f, 0.f, 0.f};
        #pragma unroll
        for (int nt = 0; nt < 12; ++nt) {
            int row = nt * 16 + li;
            bf16x8 b0 = *(const bf16x8*)((char*)Whh0s + row * 128 + ((lh ^ (row & 7)) << 4));
            bf16x8 b1 = *(const bf16x8*)((char*)Whh0s + row * 128 + (((4 + lh) ^ (row & 7)) << 4));
            acc[nt] = __builtin_amdgcn_mfma_f32_16x16x32_bf16(a0_0, b0, acc[nt], 0, 0, 0);
            acc[nt] = __builtin_amdgcn_mfma_f32_16x16x32_bf16(a0_1, b1, acc[nt], 0, 0, 0);
        }
        #pragma unroll
        for (int reg = 0; reg < 4; ++reg) {
            int ml = w * 16 + lh * 4 + reg;
            #pragma unroll
            for (int fi = 0; fi < 4; ++fi) {
                int j = li + 16 * fi;
                float hprev = b2f(*(const unsigned short*)((char*)hn1s + ml * 128 +
                                  ((((j >> 3) ^ (ml & 7))) << 4) + (j & 7) * 2));
                float gr = acc[fi][reg]     + bh0_[0][fi];
                float gz = acc[4 + fi][reg] + bh0_[1][fi];
                float gn = acc[8 + fi][reg] + bh0_[2][fi];
                float x = x4[reg];
                float r = sigf(x * wi_[0][fi] + bi0_[0][fi] + gr);
                float z = sigf(x * wi_[1][fi] + bi0_[1][fi] + gz);
                float n = tanhf_(x * wi_[2][fi] + bi0_[2][fi] + r * gn);
                float h0v = (1.f - z) * n + z * hprev;
                *(unsigned short*)((char*)hn0s + ml * 128 +
                    ((((j >> 3) ^ (ml & 7))) << 4) + (j & 7) * 2) = f2b(h0v);
            }
        }
        __syncthreads();   // hn0s ready; old hn1s fully consumed

        // ---- GRU1 matvec: gi1 = hn0(16x64) @ Wih1^T ----
        bf16x8 a1_0, a1_1;
        {
            int row = w * 16 + li;
            a1_0 = *(const bf16x8*)((char*)hn0s + row * 128 + ((lh ^ (row & 7)) << 4));
            a1_1 = *(const bf16x8*)((char*)hn0s + row * 128 + (((4 + lh) ^ (row & 7)) << 4));
        }
        #pragma unroll
        for (int nt = 0; nt < 12; ++nt) acc[nt] = (f32x4){0.f, 0.f, 0.f, 0.f};
        #pragma unroll
        for (int nt = 0; nt < 12; ++nt) {
            int row = nt * 16 + li;
            bf16x8 b0 = *(const bf16x8*)((char*)Wih1s + row * 128 + ((lh ^ (row & 7)) << 4));
            bf16x8 b1 = *(const bf16x8*)((char*)Wih1s + row * 128 + (((4 + lh) ^ (row & 7)) << 4));
            acc[nt] = __builtin_amdgcn_mfma_f32_16x16x32_bf16(a1_0, b0, acc[nt], 0, 0, 0);
            acc[nt] = __builtin_amdgcn_mfma_f32_16x16x32_bf16(a1_1, b1, acc[nt], 0, 0, 0);
        }
        #pragma unroll
        for (int fi = 0; fi < 4; ++fi) {
            int ko = li + 16 * fi;
            #pragma unroll
            for (int reg = 0; reg < 4; ++reg) {
                int ml = w * 16 + lh * 4 + reg;
                float r = sigf(acc[fi][reg]     + bi1_[0][fi] + vrA[fi][reg]);
                float z = sigf(acc[4 + fi][reg] + bi1_[1][fi] + vzA[fi][reg]);
                float n = tanhf_(acc[8 + fi][reg] + bi1_[2][fi] + r * vnA[fi][reg]);
                float h1v = (1.f - z) * n + z * h01A[fi][reg];
                *(unsigned short*)((char*)hn1s + ml * 128 +
                    ((((ko >> 3) ^ (ml & 7))) << 4) + (ko & 7) * 2) = f2b(h1v);
            }
        }
        __syncthreads();   // hn1s (new state) ready

        // ---- XPT write (transposed bf16 rows [c][m]) ----
        {
            unsigned short* XPT = XPT_c + (size_t)ts * (D_ * B_ * M_);
            int d = tid >> 1, mh = (tid & 1) * 32;
            const char* src = (d < 64) ? (const char*)hn0s : (const char*)hn1s;
            int dd = d & 63;
            unsigned int pk[16];
            #pragma unroll
            for (int mm = 0; mm < 32; mm += 2) {
                int ma = mh + mm, mb = mh + mm + 1;
                unsigned int ua = *(const unsigned short*)(src + ma * 128 + (((dd >> 3) ^ (ma & 7)) << 4) + (dd & 7) * 2);
                unsigned int ub = *(const unsigned short*)(src + mb * 128 + (((dd >> 3) ^ (mb & 7)) << 4) + (dd & 7) * 2);
                pk[mm >> 1] = ua | (ub << 16);
            }
            #pragma unroll
            for (int q = 0; q < 4; ++q) {
                uint4 o = {pk[q * 4], pk[q * 4 + 1], pk[q * 4 + 2], pk[q * 4 + 3]};
                *(uint4*)&XPT[(b * D_ + d) * M_ + m0 + mh + q * 8] = o;
            }
        }
    }

    // state writeback for next chunk
    #pragma unroll
    for (int it = 0; it < 2; ++it) {
        int idx = tid + it * 256;
        int p = idx >> 3, cc = idx & 7;
        uint4 v = *(const uint4*)((char*)hn1s + p * 128 + ((cc ^ (p & 7)) << 4));
        *(uint4*)&Hb[(p0b + p) * HD_ + cc * 8] = v;
    }
}

// ---------------- per-chunk: 256x256 pipelined graph GEMM + fused head ------
// grid (256 n-tiles, 4 m-tiles), 512 thr (8 waves, 2M x 4N).
// Triple-buffered LDS staging (tile kt reads buf[kt%3], stages kt+2 into
// buf[(kt+2)%3] -- disjoint by construction), counted vmcnt(4), raw barriers.
__global__ __launch_bounds__(512, 2) void gemmhead_kernel(
    const unsigned short* __restrict__ GTb, const unsigned short* __restrict__ XPT_c,
    const unsigned short* __restrict__ Wnb, const float* __restrict__ b_lin,
    const float* __restrict__ W_fr, const float* __restrict__ b_fr,
    float* __restrict__ out, int t0)
{
    __shared__ __align__(16) char lds[131072];  // 3 x 32KB staging; reused as XGs 128KB
    const int tid = threadIdx.x, w = tid >> 6, l = tid & 63;
    const int li = l & 15, lh = l >> 4;      // lh in 0..3
    const int wm = w >> 2, wn = w & 3;
    const int ntile = blockIdx.x;            // 0..255
    const int j0 = blockIdx.y * 256;
    const unsigned short* Asrc = GTb + (size_t)j0 * M_;
    const unsigned short* Bsrc = XPT_c + (size_t)ntile * 256 * M_;

    f32x4 acc[8][4];
    #pragma unroll
    for (int mi = 0; mi < 8; ++mi)
        #pragma unroll
        for (int ni = 0; ni < 4; ++ni) acc[mi][ni] = (f32x4){0.f, 0.f, 0.f, 0.f};

    // stage one 256x32 bf16 tile (1024 16B-chunks, 2 gloads/thread),
    // source pre-swizzled (chunk pos ^ (row&3)) so linear LDS = swizzled layout
    #define STAGE_A(kt, c) { \
        _Pragma("unroll") \
        for (int rr = 0; rr < 2; ++rr) { \
            int i = rr * 512 + tid; \
            int row = i >> 2, pos = i & 3, sc = pos ^ (row & 3); \
            gload16(&Asrc[row * M_ + (kt) * 32 + sc * 8], lds + (c) * 32768 + (i & ~63) * 16); \
        } }
    #define STAGE_B(kt, c) { \
        _Pragma("unroll") \
        for (int rr = 0; rr < 2; ++rr) { \
            int i = rr * 512 + tid; \
            int row = i >> 2, pos = i & 3, sc = pos ^ (row & 3); \
            gload16(&Bsrc[row * M_ + (kt) * 32 + sc * 8], lds + (c) * 32768 + 16384 + (i & ~63) * 16); \
        } }

    STAGE_A(0, 0); STAGE_B(0, 0);
    STAGE_A(1, 1); STAGE_B(1, 1);

    for (int kt = 0; kt < NKT; ++kt) {
        if (kt < NKT - 1) { asm volatile("s_waitcnt vmcnt(4)" ::: "memory"); }
        else              { asm volatile("s_waitcnt vmcnt(0)" ::: "memory"); }
        __builtin_amdgcn_s_barrier();
        asm volatile("" ::: "memory");   // keep LDS reads below the barrier
        const int cur = kt % 3;
        const char* Abuf = lds + cur * 32768;
        const char* Bbuf = lds + cur * 32768 + 16384;
        bf16x8 afr[8], bfr[4];
        // phase 0: frags (B all, A lower half) + stage A(kt+2) + 16 MFMA
        #pragma unroll
        for (int ni = 0; ni < 4; ++ni) {
            int row = wn * 64 + ni * 16 + li;
            bfr[ni] = *(const bf16x8*)(Bbuf + row * 64 + ((lh ^ (row & 3)) << 4));
        }
        #pragma unroll
        for (int mi = 0; mi < 4; ++mi) {
            int row = wm * 128 + mi * 16 + li;
            afr[mi] = *(const bf16x8*)(Abuf + row * 64 + ((lh ^ (row & 3)) << 4));
        }
        if (kt + 2 < NKT) STAGE_A(kt + 2, (kt + 2) % 3);
        __builtin_amdgcn_s_setprio(1);
        #pragma unroll
        for (int mi = 0; mi < 4; ++mi)
            #pragma unroll
            for (int ni = 0; ni < 4; ++ni)
                acc[mi][ni] = __builtin_amdgcn_mfma_f32_16x16x32_bf16(afr[mi], bfr[ni], acc[mi][ni], 0, 0, 0);
        __builtin_amdgcn_s_setprio(0);
        // phase 1: frags (A upper half) + stage B(kt+2) + 16 MFMA
        #pragma unroll
        for (int mi = 4; mi < 8; ++mi) {
            int row = wm * 128 + mi * 16 + li;
            afr[mi] = *(const bf16x8*)(Abuf + row * 64 + ((lh ^ (row & 3)) << 4));
        }
        if (kt + 2 < NKT) STAGE_B(kt + 2, (kt + 2) % 3);
        __builtin_amdgcn_s_setprio(1);
        #pragma unroll
        for (int mi = 4; mi < 8; ++mi)
            #pragma unroll
            for (int ni = 0; ni < 4; ++ni)
                acc[mi][ni] = __builtin_amdgcn_mfma_f32_16x16x32_bf16(afr[mi], bfr[ni], acc[mi][ni], 0, 0, 0);
        __builtin_amdgcn_s_setprio(0);
    }

    __syncthreads();   // all staging drained (vmcnt0 at kt=31); free LDS for XGs

    // relu -> bf16 -> XGs[256][256] (row stride 512B, 16B-chunk XOR swizzle)
    #pragma unroll
    for (int mi = 0; mi < 8; ++mi)
        #pragma unroll
        for (int ni = 0; ni < 4; ++ni)
            #pragma unroll
            for (int reg = 0; reg < 4; ++reg) {
                int jl = wm * 128 + mi * 16 + lh * 4 + reg;
                int cl = wn * 64 + ni * 16 + li;
                float v = fmaxf(acc[mi][ni][reg], 0.f);
                int byte = jl * 512 + ((((cl >> 3) ^ (jl & 7))) << 4) + (cl & 7) * 2;
                *(unsigned short*)(lds + byte) = f2b(v);
            }
    __syncthreads();

    // head: per panel p (b = b0+p), P[j][r] = XG[j][p*128:] . Wn[r][:]
    const int ts = ntile >> 4, b0 = (ntile & 15) * 2;
    const int t = t0 + ts;
    float bl0 = b_lin[li], bl1 = b_lin[16 + li];
    #pragma unroll
    for (int rg = 0; rg < 2; ++rg) {
        int row = w * 32 + rg * 16 + li;
        #pragma unroll
        for (int p = 0; p < 2; ++p) {
            f32x4 P0 = (f32x4){0.f, 0.f, 0.f, 0.f};
            f32x4 P1 = (f32x4){0.f, 0.f, 0.f, 0.f};
            #pragma unroll
            for (int ks = 0; ks < 4; ++ks) {
                int cp = (p * 16 + ks * 4 + lh) ^ (row & 7);
                bf16x8 xa = *(const bf16x8*)(lds + row * 512 + cp * 16);
                bf16x8 wb0 = *(const bf16x8*)&Wnb[(li) * D_ + ks * 32 + lh * 8];
                bf16x8 wb1 = *(const bf16x8*)&Wnb[(16 + li) * D_ + ks * 32 + lh * 8];
                P0 = __builtin_amdgcn_mfma_f32_16x16x32_bf16(xa, wb0, P0, 0, 0, 0);
                P1 = __builtin_amdgcn_mfma_f32_16x16x32_bf16(xa, wb1, P1, 0, 0, 0);
            }
            float s[4];
            #pragma unroll
            for (int reg = 0; reg < 4; ++reg) {
                int j = j0 + w * 32 + rg * 16 + lh * 4 + reg;
                float y0 = sigf(P0[reg] + bl0);
                float y1 = sigf(P1[reg] + bl1);
                s[reg] = y0 * W_fr[j * RD_ + li] + y1 * W_fr[j * RD_ + 16 + li];
            }
            #pragma unroll
            for (int off = 1; off < 16; off <<= 1) {
                #pragma unroll
                for (int reg = 0; reg < 4; ++reg) s[reg] += __shfl_xor(s[reg], off);
            }
            if (li == 0) {
                int jb = j0 + w * 32 + rg * 16 + lh * 4;
                float4 o = {s[0] + b_fr[jb], s[1] + b_fr[jb + 1],
                            s[2] + b_fr[jb + 2], s[3] + b_fr[jb + 3]};
                *(float4*)&out[((b0 + p) * W_ + t) * M_ + jb] = o;
            }
        }
    }
}

// ---------------- launcher ----------------

extern "C" void kernel_launch(void* const* d_in, const int* in_sizes, int n_in,
                              void* d_out, int out_size, void* d_ws, size_t ws_size,
                              hipStream_t stream) {
    const float* x_input = (const float*)d_in[0];
    const float* G       = (const float*)d_in[1];
    const float* H_init  = (const float*)d_in[2];
    const float* Wih0    = (const float*)d_in[3];
    const float* Whh0    = (const float*)d_in[4];
    const float* bih0    = (const float*)d_in[5];
    const float* bhh0    = (const float*)d_in[6];
    const float* Wih1    = (const float*)d_in[7];
    const float* Whh1    = (const float*)d_in[8];
    const float* bih1    = (const float*)d_in[9];
    const float* bhh1    = (const float*)d_in[10];
    const float* V       = (const float*)d_in[11];
    const float* gvec    = (const float*)d_in[12];
    const float* b_lin   = (const float*)d_in[13];
    const float* W_fr    = (const float*)d_in[14];
    const float* b_fr    = (const float*)d_in[15];
    float* out = (float*)d_out;

    // ws layout (bytes), total ~135.1 MiB of the 256 MiB workspace
    char* ws = (char*)d_ws;
    unsigned short* GTb   = (unsigned short*)(ws);                   //   2 MiB
    unsigned short* XPT_c = (unsigned short*)(ws + (2u   << 20));    // 128 MiB (16 steps x 8 MiB)
    unsigned short* Hb    = (unsigned short*)(ws + (130u << 20));    //   4 MiB
    float*          gh1cT = (float*)(ws + (134u << 20));             // 768 KiB
    unsigned short* Wnb   = (unsigned short*)(ws + (135u << 20));    //   8 KiB
    unsigned short* Whh0b = (unsigned short*)(ws + (135u << 20) + 8192);
    unsigned short* Wih1b = (unsigned short*)(ws + (135u << 20) + 8192 + 24576);

    gt_kernel   <<<dim3(16, 16), 256, 0, stream>>>(G, GTb);
    gh1ct_kernel<<<M_, 192, 0, stream>>>(H_init, Whh1, bhh1, gh1cT);
    wn_kernel   <<<RD_, 128, 0, stream>>>(V, gvec, Wnb);
    castw_kernel<<<48, 256, 0, stream>>>(Whh0, Wih1, Whh0b, Wih1b);
    inith_kernel<<<1024, 256, 0, stream>>>(H_init, Hb);

    for (int c = 0; c < W_ / CH_; ++c) {
        gru_chunk_kernel<<<512, 256, 0, stream>>>(x_input, Wih0, bih0, bhh0, Whh0b,
                                                  Wih1b, bih1, gh1cT, H_init, Hb,
                                                  XPT_c, c * CH_);
        gemmhead_kernel<<<dim3(256, 4), 512, 0, stream>>>(GTb, XPT_c, Wnb, b_lin,
                                                          W_fr, b_fr, out, c * CH_);
    }
}